// Round 20
// baseline (194.612 us; speedup 1.0000x reference)
//
#include <hip/hip_runtime.h>
#include <cstdint>

#define DEVI static __device__ __forceinline__

typedef __attribute__((ext_vector_type(8))) short bf16x8;
typedef __attribute__((ext_vector_type(4))) float f32x4;
typedef __attribute__((ext_vector_type(8))) unsigned short ush8;

DEVI unsigned short f2bf(float f) {
    unsigned u = __float_as_uint(f);
    u += 0x7fff + ((u >> 16) & 1);
    return (unsigned short)(u >> 16);
}
DEVI float bf2f(unsigned short h) { return __uint_as_float(((unsigned)h) << 16); }

DEVI void gload16(const void* g, void* l) {
    __builtin_amdgcn_global_load_lds((const __attribute__((address_space(1))) void*)g,
                                     (__attribute__((address_space(3))) void*)l, 16, 0, 0);
}

DEVI float fast_gelu(float x) {
    // tanh-approx GELU via raw v_rcp_f32 (no -ffast-math; '/' would expand to ~12-op exact div)
    float z = 1.5957691216057308f * (x + 0.044715f * x * x * x);
    return x - x * __builtin_amdgcn_rcpf(__expf(z) + 1.f);
}

// ---------------- weight pack: fp32 -> bf16 in MFMA-fragment order ----------------
__global__ __launch_bounds__(256) void k_pack(const float* __restrict__ Wq, const float* __restrict__ Wkv,
                                              const float* __restrict__ Wp, const float* __restrict__ Wf1,
                                              const float* __restrict__ Wf2, unsigned short* __restrict__ dst) {
    int t = blockIdx.x * 256 + threadIdx.x;
    if (t >= 55296) return;
    int c, base, K;
    const float* src = nullptr;
    if (t < 13824)      { c = t;         base = 0;      K = 192; }
    else if (t < 18432) { c = t - 13824; base = 110592; K = 192; src = Wp; }
    else if (t < 36864) { c = t - 18432; base = 147456; K = 192; src = Wf1; }
    else                { c = t - 36864; base = 294912; K = 768; src = Wf2; }
    int lane = c & 63, fk = c >> 6, Kf = K >> 5;
    int kf = fk % Kf, nf = fk / Kf;
    int row = nf * 16 + (lane & 15), col = kf * 32 + (lane >> 4) * 8;
    ush8 o;
    if (t < 13824) {
        if (row < 192) {
            #pragma unroll
            for (int q = 0; q < 8; q++) o[q] = f2bf(Wq[row * 192 + col + q] * 0.17677669529663687f);
        } else {
            #pragma unroll
            for (int q = 0; q < 8; q++) o[q] = f2bf(Wkv[(row - 192) * 192 + col + q]);
        }
    } else {
        #pragma unroll
        for (int q = 0; q < 8; q++) o[q] = f2bf(src[(long)row * K + col + q]);
    }
    *(ush8*)&dst[base + c * 8] = o;
}

// ---------------- fused bias+mask table: [6 heads][8 variants][128 i][16 li][8 fn] f32 ----------------
__global__ __launch_bounds__(256) void k_bmt(const float* __restrict__ rpb, float* __restrict__ bmt) {
    int t = blockIdx.x * 256 + threadIdx.x;  // 6 * 131072
    int h = t >> 17;
    int r = t & 131071;
    int v = r >> 14;
    int ij = r & 16383;
    int i = ij >> 7, li = (ij >> 3) & 15, fn = ij & 7;
    int j = fn * 16 + li;
    int tdi = i >> 6, thi = (i >> 3) & 7, twi = i & 7;
    int tdj = j >> 6, thj = (j >> 3) & 7, twj = j & 7;
    int idx = ((tdi - tdj + 1) * 15 + (thi - thj + 7)) * 15 + (twi - twj + 7);
    float b = rpb[idx * 6 + h];
    int dwb = v & 1, hwb = (v >> 1) & 1, wwb = (v >> 2) & 1;
    int ri = (dwb ? 1 + tdi : 0) * 9 + (hwb ? (thi < 4 ? 1 : 2) : 0) * 3 + (wwb ? (twi < 4 ? 1 : 2) : 0);
    int rj = (dwb ? 1 + tdj : 0) * 9 + (hwb ? (thj < 4 ? 1 : 2) : 0) * 3 + (wwb ? (twj < 4 ? 1 : 2) : 0);
    if (ri != rj) b -= 100.f;
    bmt[(long)(h * 8 + v) * 16384 + i * 128 + li * 8 + fn] = b;
}

// ---------------- LayerNorm fused with roll+window gather ----------------
__global__ __launch_bounds__(256) void k_ln(const float* __restrict__ x, const float* __restrict__ g,
                                            const float* __restrict__ b, unsigned short* __restrict__ outp) {
    int wid = threadIdx.x >> 6, lane = threadIdx.x & 63;
    int t = blockIdx.x * 4 + wid;
    int w = t >> 7, tt = t & 127;
    int bb = w >> 8, rem = w & 255;
    int dw = rem >> 6, hw = (rem >> 3) & 7, ww = rem & 7;
    int td = tt >> 6, th = (tt >> 3) & 7, tw = tt & 7;
    int d = (dw * 2 + td + 1) & 7;
    int hh = (hw * 8 + th + 4) & 63;
    int wo = (ww * 8 + tw + 4) & 63;
    long src = (long)((bb * 8 + d) * 64 + hh) * 64 + wo;
    const float* xp = x + src * 192;
    float v0 = xp[lane], v1 = xp[lane + 64], v2 = xp[lane + 128];
    float s = v0 + v1 + v2, ss = v0 * v0 + v1 * v1 + v2 * v2;
    #pragma unroll
    for (int m = 32; m; m >>= 1) { s += __shfl_xor(s, m); ss += __shfl_xor(ss, m); }
    float mu = s * (1.f / 192.f);
    float var = ss * (1.f / 192.f) - mu * mu;
    float inv = rsqrtf(var + 1e-5f);
    unsigned short* op = outp + (long)t * 192;
    op[lane]       = f2bf((v0 - mu) * inv * g[lane]       + b[lane]);
    op[lane + 64]  = f2bf((v1 - mu) * inv * g[lane + 64]  + b[lane + 64]);
    op[lane + 128] = f2bf((v2 - mu) * inv * g[lane + 128] + b[lane + 128]);
}

// ---------------- bf16 MFMA GEMM: C[M,N] = A[M,K] @ B[N,K]^T, B in packed-frag form ----------------
// EPI: 1=proj + window-reverse + residual -> x1 bf16
template <int EPI>
__global__ __launch_bounds__(256, 4) void k_gemm(const unsigned short* __restrict__ A,
                                                 const unsigned short* __restrict__ Bpk, int K,
                                                 const float* __restrict__ bias,
                                                 const float* __restrict__ addsrc,
                                                 unsigned short* __restrict__ outU) {
    __shared__ __align__(16) unsigned short As[2][256 * 32];
    int tid = threadIdx.x;
    int wid = tid >> 6, lane = tid & 63;
    int g = lane >> 4, li = lane & 15;
    int m0 = blockIdx.y * 256, n0 = blockIdx.x * 64;
    int Kf = K >> 5;

    f32x4 acc[4][4];
    #pragma unroll
    for (int i = 0; i < 4; i++)
        #pragma unroll
        for (int j = 0; j < 4; j++) acc[i][j] = (f32x4){0.f, 0.f, 0.f, 0.f};

    int sg = ((tid & 3) ^ ((tid >> 3) & 3)) * 8;
    const unsigned short* pa = A + (long)(m0 + (tid >> 2)) * K + sg;
    const unsigned short* pbk = Bpk + ((long)(n0 >> 4) * Kf * 64 + lane) * 8;

#define STAGE(buf, kt) do { \
    _Pragma("unroll") \
    for (int c = 0; c < 4; c++) \
        gload16(pa + (long)(c * 64) * K + (kt), &As[buf][c * 2048 + tid * 8]); \
} while (0)

    STAGE(0, 0);
    __syncthreads();

    int cur = 0;
    int acol = (g ^ ((li >> 1) & 3)) * 8;
    for (int t = 0; t < Kf; t++) {
        bf16x8 bfr[4];
        #pragma unroll
        for (int j = 0; j < 4; j++)
            bfr[j] = *(const bf16x8*)(pbk + ((long)j * Kf + t) * 512);
        if (t + 1 < Kf) STAGE(cur ^ 1, (t + 1) << 5);
        const unsigned short* ab = &As[cur][(wid * 64 + li) * 32 + acol];
        bf16x8 af[4];
        #pragma unroll
        for (int i = 0; i < 4; i++) af[i] = *(const bf16x8*)(ab + i * 512);
        __builtin_amdgcn_s_setprio(1);
        #pragma unroll
        for (int i = 0; i < 4; i++)
            #pragma unroll
            for (int j = 0; j < 4; j++)
                acc[i][j] = __builtin_amdgcn_mfma_f32_16x16x32_bf16(af[i], bfr[j], acc[i][j], 0, 0, 0);
        __builtin_amdgcn_s_setprio(0);
        if (t + 1 < Kf) {
            __syncthreads();
            cur ^= 1;
        }
    }
#undef STAGE

    #pragma unroll
    for (int i = 0; i < 4; i++) {
        int rowb = m0 + wid * 64 + i * 16 + g * 4;
        #pragma unroll
        for (int j = 0; j < 4; j++) {
            int col = n0 + j * 16 + li;
            #pragma unroll
            for (int r = 0; r < 4; r++) {
                float v = acc[i][j][r];
                int rr = rowb + r;
                {
                    int w = rr >> 7, tt = rr & 127;
                    int bb2 = w >> 8, rem = w & 255;
                    int dw = rem >> 6, hw = (rem >> 3) & 7, ww = rem & 7;
                    int td = tt >> 6, th = (tt >> 3) & 7, tw = tt & 7;
                    int d = (dw * 2 + td + 1) & 7;
                    int hh = (hw * 8 + th + 4) & 63;
                    int wo = (ww * 8 + tw + 4) & 63;
                    long src = ((long)((bb2 * 8 + d) * 64 + hh) * 64 + wo) * 192 + col;
                    outU[src] = f2bf(addsrc[src] + v + bias[col]);   // x1 in bf16
                }
            }
        }
    }
}

// ---------------- fused LN2 + MLP1 + GELU + MLP2 + residual (x1 in bf16) ----------------
// One block = 64 token rows, 512 threads (8 waves). LDS in MFMA-FRAGMENT-PACKED layout
// (frag = 64 lanes x 16B contiguous -> conflict-free 1KB wave reads). 40KB LDS.
__global__ __launch_bounds__(512, 4) void k_mlp(const unsigned short* __restrict__ x1,
                                                const float* __restrict__ g2, const float* __restrict__ b2,
                                                const unsigned short* __restrict__ wf1pk,
                                                const unsigned short* __restrict__ wf2pk,
                                                const float* __restrict__ bf1v, const float* __restrict__ bf2v,
                                                float* __restrict__ out) {
    __shared__ __align__(16) unsigned short A_s[24 * 512];  // 24576 B
    __shared__ __align__(16) unsigned short H_s[16 * 512];  // 16384 B
    int tid = threadIdx.x;
    int wid = tid >> 6, lane = tid & 63;
    int g = lane >> 4, li = lane & 15;
    long r0 = (long)blockIdx.x * 64;

    // ---- LN2 stage: 8 threads per row, 24 bf16 each; write in packed-frag layout ----
    {
        int row = tid >> 3;
        int c0 = (tid & 7) * 24;
        const unsigned short* xp = x1 + (r0 + row) * 192 + c0;
        float v[24];
        #pragma unroll
        for (int q = 0; q < 3; q++) {
            ush8 f = *(const ush8*)(xp + q * 8);
            #pragma unroll
            for (int e = 0; e < 8; e++) v[q * 8 + e] = bf2f(f[e]);
        }
        float s = 0.f, ss = 0.f;
        #pragma unroll
        for (int q = 0; q < 24; q++) { s += v[q]; ss += v[q] * v[q]; }
        #pragma unroll
        for (int m = 1; m < 8; m <<= 1) { s += __shfl_xor(s, m); ss += __shfl_xor(ss, m); }
        float mu = s * (1.f / 192.f);
        float var = ss * (1.f / 192.f) - mu * mu;
        float inv = rsqrtf(var + 1e-5f);
        ush8 o[3];
        #pragma unroll
        for (int q = 0; q < 24; q++) {
            float gv = g2[c0 + q], bv = b2[c0 + q];
            o[q >> 3][q & 7] = f2bf((v[q] - mu) * inv * gv + bv);
        }
        #pragma unroll
        for (int q = 0; q < 3; q++) {
            int cb = c0 + q * 8;
            int fi = (row >> 4) * 6 + (cb >> 5);            // frag index (mf*6+kf)
            int l2 = (((cb >> 3) & 3) << 4) | (row & 15);   // dest lane in frag
            *(ush8*)&A_s[(fi * 64 + l2) * 8] = o[q];
        }
    }
    __syncthreads();

    int mw = wid >> 2, nw = wid & 3;            // GEMM2 roles: token half, out-col quarter
    int kf2 = wid >> 1;                          // this wave's hidden-frag in GEMM1 output
    int gpos = ((wid & 1) << 1) | (li >> 3);     // position-in-frag for H writes
    int e = li & 7;
    f32x4 acc2[2][3];
    #pragma unroll
    for (int i = 0; i < 2; i++)
        #pragma unroll
        for (int j = 0; j < 3; j++) acc2[i][j] = (f32x4){0.f, 0.f, 0.f, 0.f};

    for (int ch = 0; ch < 6; ch++) {
        // GEMM1: wave owns hidden frag nf = ch*8 + wid (16 cols), all 64 tokens
        f32x4 acc1[4];
        #pragma unroll
        for (int i = 0; i < 4; i++) acc1[i] = (f32x4){0.f, 0.f, 0.f, 0.f};
        int nf = ch * 8 + wid;
        float bv1 = bf1v[ch * 128 + wid * 16 + li];
        #pragma unroll
        for (int kf = 0; kf < 6; kf++) {
            bf16x8 b = *(const bf16x8*)&wf1pk[(((long)nf * 6 + kf) * 64 + lane) * 8];
            __builtin_amdgcn_s_setprio(1);
            #pragma unroll
            for (int mf = 0; mf < 4; mf++) {
                bf16x8 a = *(const bf16x8*)&A_s[(((mf * 6 + kf) * 64) + lane) * 8];
                acc1[mf] = __builtin_amdgcn_mfma_f32_16x16x32_bf16(a, b, acc1[mf], 0, 0, 0);
            }
            __builtin_amdgcn_s_setprio(0);
        }
        // hoist W2 loads for kf=0,1 across the barrier
        bf16x8 w2p[2][3];
        #pragma unroll
        for (int kf = 0; kf < 2; kf++)
            #pragma unroll
            for (int jf = 0; jf < 3; jf++)
                w2p[kf][jf] = *(const bf16x8*)&wf2pk[(((long)(nw * 3 + jf) * 24 + ch * 4 + kf) * 64 + lane) * 8];
        // bias + gelu + write H chunk in packed-frag layout
        #pragma unroll
        for (int mf = 0; mf < 4; mf++)
            #pragma unroll
            for (int r = 0; r < 4; r++) {
                int l2 = (gpos << 4) | (g * 4 + r);
                H_s[((mf * 4 + kf2) * 64 + l2) * 8 + e] = f2bf(fast_gelu(acc1[mf][r] + bv1));
            }
        __syncthreads();
        // GEMM2 partial: out[mw*32.., nw*48..] += H_chunk @ Wf2[:, ch-cols]^T
        #pragma unroll
        for (int kf = 0; kf < 4; kf++) {
            bf16x8 hf[2], bf[3];
            #pragma unroll
            for (int mf = 0; mf < 2; mf++)
                hf[mf] = *(const bf16x8*)&H_s[(((mw * 2 + mf) * 4 + kf) * 64 + lane) * 8];
            if (kf < 2) {
                #pragma unroll
                for (int jf = 0; jf < 3; jf++) bf[jf] = w2p[kf][jf];
            } else {
                #pragma unroll
                for (int jf = 0; jf < 3; jf++)
                    bf[jf] = *(const bf16x8*)&wf2pk[(((long)(nw * 3 + jf) * 24 + ch * 4 + kf) * 64 + lane) * 8];
            }
            __builtin_amdgcn_s_setprio(1);
            #pragma unroll
            for (int mf = 0; mf < 2; mf++)
                #pragma unroll
                for (int jf = 0; jf < 3; jf++)
                    acc2[mf][jf] = __builtin_amdgcn_mfma_f32_16x16x32_bf16(hf[mf], bf[jf], acc2[mf][jf], 0, 0, 0);
            __builtin_amdgcn_s_setprio(0);
        }
        __syncthreads();
    }

    // epilogue: out = x1 + acc2 + bf2
    #pragma unroll
    for (int mf = 0; mf < 2; mf++) {
        #pragma unroll
        for (int jf = 0; jf < 3; jf++) {
            int col = nw * 48 + jf * 16 + li;
            float bv = bf2v[col];
            #pragma unroll
            for (int r = 0; r < 4; r++) {
                int row = mw * 32 + mf * 16 + g * 4 + r;
                long idx = (r0 + row) * 192 + col;
                out[idx] = bf2f(x1[idx]) + acc2[mf][jf][r] + bv;
            }
        }
    }
}

// ---------------- attention with fused QKV: 3072 blocks, XCD-swizzled, 512 threads ----------------
// Block b -> xcd x=b%8, slot j=b/8 -> window w = x + 8*(j/6), head h = j%6 (same-XCD windows).
// 8 waves: wave wid owns 16 tokens. QKV 36 MFMA/wave, QK^T 8, PV 8 -> short phases,
// 16 waves/CU for latency hiding.
__global__ __launch_bounds__(512, 4) void k_attn(const unsigned short* __restrict__ xw,
                                                 const unsigned short* __restrict__ qkvpk,
                                                 const float* __restrict__ bmt,
                                                 unsigned short* __restrict__ attnout) {
    __shared__ __align__(16) char smem[78336];
    unsigned short* xw_s = (unsigned short*)smem;            // [128][200] = 51200B, dead after QKV
    unsigned short* p_s  = (unsigned short*)smem;            // [128][132] = 33792B, overlays xw_s
    unsigned short* q_s  = (unsigned short*)(smem + 51200);  // [128][36]  = 9216B
    unsigned short* k_s  = (unsigned short*)(smem + 60416);  // [128][36]  = 9216B
    unsigned short* vt_s = (unsigned short*)(smem + 69632);  // [32][136]  = 8704B

    int b = blockIdx.x;
    int xcd = b & 7, j = b >> 3;
    int w = xcd + 8 * (j / 6), h = j % 6;
    int tid = threadIdx.x, wid = tid >> 6, lane = tid & 63, g = lane >> 4, li = lane & 15;
    int rem = w & 255;
    int dw = rem >> 6, hw = (rem >> 3) & 7, ww = rem & 7;
    int variant = (dw == 3 ? 1 : 0) | (hw == 7 ? 2 : 0) | (ww == 7 ? 4 : 0);
    const float* bm = bmt + (long)(h * 8 + variant) * 16384;

    // ---- stage xw tile [128][192] -> padded LDS [128][200] ----
    {
        int r = tid >> 2, part = tid & 3;
        const unsigned short* src = xw + ((long)w * 128 + r) * 192 + part * 48;
        #pragma unroll
        for (int jj = 0; jj < 6; jj++)
            *(uint4*)&xw_s[r * 200 + part * 48 + jj * 8] = *(const uint4*)(src + jj * 8);
    }
    __syncthreads();

    // ---- QKV: wave wid owns tokens wid*16..+15; out frags jj: {q0,q1,k0,k1,v0,v1} ----
    f32x4 qk[6];
    #pragma unroll
    for (int jj = 0; jj < 6; jj++) qk[jj] = (f32x4){0.f, 0.f, 0.f, 0.f};
    #pragma unroll
    for (int kf = 0; kf < 6; kf++) {
        bf16x8 a = *(const bf16x8*)&xw_s[(wid * 16 + li) * 200 + kf * 32 + g * 8];
        __builtin_amdgcn_s_setprio(1);
        #pragma unroll
        for (int jj = 0; jj < 6; jj++) {
            int nf = (jj >> 1) * 12 + 2 * h + (jj & 1);
            bf16x8 bw = *(const bf16x8*)&qkvpk[(((long)nf * 6 + kf) * 64 + lane) * 8];
            qk[jj] = __builtin_amdgcn_mfma_f32_16x16x32_bf16(a, bw, qk[jj], 0, 0, 0);
        }
        __builtin_amdgcn_s_setprio(0);
    }
    // scatter q/k/v into LDS (col=li, row=token g*4+r per C/D layout)
    {
        int tokb = wid * 16 + g * 4;
        #pragma unroll
        for (int r = 0; r < 4; r++) {
            int tok = tokb + r;
            q_s[tok * 36 + li]          = f2bf(qk[0][r]);
            q_s[tok * 36 + 16 + li]     = f2bf(qk[1][r]);
            k_s[tok * 36 + li]          = f2bf(qk[2][r]);
            k_s[tok * 36 + 16 + li]     = f2bf(qk[3][r]);
            vt_s[li * 136 + tok]        = f2bf(qk[4][r]);
            vt_s[(16 + li) * 136 + tok] = f2bf(qk[5][r]);
        }
    }
    __syncthreads();   // all xw_s reads done; p_s may overlay from here on

    // ---- QK^T: wave wid owns query rows wid*16..+15 ----
    f32x4 s[8];
    #pragma unroll
    for (int jj = 0; jj < 8; jj++) s[jj] = (f32x4){0.f, 0.f, 0.f, 0.f};
    bf16x8 qa = *(const bf16x8*)&q_s[(wid * 16 + li) * 36 + g * 8];
    __builtin_amdgcn_s_setprio(1);
    #pragma unroll
    for (int fn = 0; fn < 8; fn++) {
        bf16x8 kb = *(const bf16x8*)&k_s[(fn * 16 + li) * 36 + g * 8];
        s[fn] = __builtin_amdgcn_mfma_f32_16x16x32_bf16(qa, kb, s[fn], 0, 0, 0);
    }
    __builtin_amdgcn_s_setprio(0);

    // ---- bias + mask + softmax (4 rows per lane-group) ----
    #pragma unroll
    for (int r = 0; r < 4; r++) {
        int i = wid * 16 + g * 4 + r;
        const float4 b0 = *(const float4*)&bm[i * 128 + li * 8];
        const float4 b1 = *(const float4*)&bm[i * 128 + li * 8 + 4];
        float vals[8];
        vals[0] = s[0][r] + b0.x; vals[1] = s[1][r] + b0.y;
        vals[2] = s[2][r] + b0.z; vals[3] = s[3][r] + b0.w;
        vals[4] = s[4][r] + b1.x; vals[5] = s[5][r] + b1.y;
        vals[6] = s[6][r] + b1.z; vals[7] = s[7][r] + b1.w;
        float mx = fmaxf(fmaxf(fmaxf(vals[0], vals[1]), fmaxf(vals[2], vals[3])),
                         fmaxf(fmaxf(vals[4], vals[5]), fmaxf(vals[6], vals[7])));
        #pragma unroll
        for (int m = 1; m < 16; m <<= 1) mx = fmaxf(mx, __shfl_xor(mx, m, 16));
        float sum = 0.f;
        #pragma unroll
        for (int fn = 0; fn < 8; fn++) { vals[fn] = __expf(vals[fn] - mx); sum += vals[fn]; }
        #pragma unroll
        for (int m = 1; m < 16; m <<= 1) sum += __shfl_xor(sum, m, 16);
        float inv = __builtin_amdgcn_rcpf(sum);
        #pragma unroll
        for (int fn = 0; fn < 8; fn++)
            p_s[i * 132 + fn * 16 + li] = f2bf(vals[fn] * inv);
    }

    // ---- PV: wave computes its 16 rows x 32 d ----
    f32x4 o[2];
    o[0] = (f32x4){0.f, 0.f, 0.f, 0.f};
    o[1] = (f32x4){0.f, 0.f, 0.f, 0.f};
    __builtin_amdgcn_s_setprio(1);
    #pragma unroll
    for (int ks = 0; ks < 4; ks++) {
        bf16x8 pa = *(const bf16x8*)&p_s[(wid * 16 + li) * 132 + ks * 32 + g * 8];
        #pragma unroll
        for (int fn = 0; fn < 2; fn++) {
            bf16x8 vb = *(const bf16x8*)&vt_s[(fn * 16 + li) * 136 + ks * 32 + g * 8];
            o[fn] = __builtin_amdgcn_mfma_f32_16x16x32_bf16(pa, vb, o[fn], 0, 0, 0);
        }
    }
    __builtin_amdgcn_s_setprio(0);

    unsigned short* op = attnout + (long)w * 128 * 192 + h * 32;
    #pragma unroll
    for (int fn = 0; fn < 2; fn++) {
        #pragma unroll
        for (int r = 0; r < 4; r++) {
            int n = wid * 16 + g * 4 + r;
            op[(long)n * 192 + fn * 16 + li] = f2bf(o[fn][r]);
        }
    }
}

// ---------------- host ----------------
extern "C" void kernel_launch(void* const* d_in, const int* in_sizes, int n_in,
                              void* d_out, int out_size, void* d_ws, size_t ws_size,
                              hipStream_t stream) {
    const float* x   = (const float*)d_in[0];
    const float* g1  = (const float*)d_in[1];
    const float* b1  = (const float*)d_in[2];
    const float* Wq  = (const float*)d_in[3];
    const float* Wkv = (const float*)d_in[4];
    const float* rpb = (const float*)d_in[5];
    const float* Wp  = (const float*)d_in[6];
    const float* bp  = (const float*)d_in[7];
    const float* g2  = (const float*)d_in[8];
    const float* b2  = (const float*)d_in[9];
    const float* Wf1 = (const float*)d_in[10];
    const float* bf1 = (const float*)d_in[11];
    const float* Wf2 = (const float*)d_in[12];
    const float* bf2 = (const float*)d_in[13];
    float* out = (float*)d_out;
    char* ws = (char*)d_ws;

    unsigned short* wpk  = (unsigned short*)ws;               // 884736 B
    float* bmt           = (float*)(ws + 917504);             // 3145728 B -> ends 4063232
    unsigned short* xw   = (unsigned short*)(ws + 4194304);   // 25165824 B -> ends 29360128
    unsigned short* attb = (unsigned short*)(ws + 29360128);  // 25165824 B -> ends 54525952
    unsigned short* x1b  = (unsigned short*)(ws + 54525952);  // 25165824 B bf16 -> ends 79691776

    const unsigned short* qkvpk = wpk;
    const unsigned short* wppk  = wpk + 110592;
    const unsigned short* wf1pk = wpk + 147456;
    const unsigned short* wf2pk = wpk + 294912;

    k_pack<<<216, 256, 0, stream>>>(Wq, Wkv, Wp, Wf1, Wf2, wpk);
    k_bmt<<<3072, 256, 0, stream>>>(rpb, bmt);
    k_ln<<<16384, 256, 0, stream>>>(x, g1, b1, xw);
    k_attn<<<3072, 512, 0, stream>>>(xw, qkvpk, bmt, attb);
    k_gemm<1><<<dim3(3, 256), 256, 0, stream>>>(attb, wppk, 192, bp, x, x1b);
    k_mlp<<<1024, 512, 0, stream>>>(x1b, g2, b2, wf1pk, wf2pk, bf1, bf2, out);
}

// Round 21
// 182.708 us; speedup vs baseline: 1.0652x; 1.0652x over previous
//
#include <hip/hip_runtime.h>
#include <cstdint>

#define DEVI static __device__ __forceinline__

typedef __attribute__((ext_vector_type(8))) short bf16x8;
typedef __attribute__((ext_vector_type(4))) float f32x4;
typedef __attribute__((ext_vector_type(8))) unsigned short ush8;

DEVI unsigned short f2bf(float f) {
    unsigned u = __float_as_uint(f);
    u += 0x7fff + ((u >> 16) & 1);
    return (unsigned short)(u >> 16);
}
DEVI float bf2f(unsigned short h) { return __uint_as_float(((unsigned)h) << 16); }

DEVI void gload16(const void* g, void* l) {
    __builtin_amdgcn_global_load_lds((const __attribute__((address_space(1))) void*)g,
                                     (__attribute__((address_space(3))) void*)l, 16, 0, 0);
}

DEVI float fast_gelu(float x) {
    // tanh-approx GELU via raw v_rcp_f32 (no -ffast-math; '/' would expand to ~12-op exact div)
    float z = 1.5957691216057308f * (x + 0.044715f * x * x * x);
    return x - x * __builtin_amdgcn_rcpf(__expf(z) + 1.f);
}

// ---------------- weight pack: fp32 -> bf16 in MFMA-fragment order ----------------
__global__ __launch_bounds__(256) void k_pack(const float* __restrict__ Wq, const float* __restrict__ Wkv,
                                              const float* __restrict__ Wp, const float* __restrict__ Wf1,
                                              const float* __restrict__ Wf2, unsigned short* __restrict__ dst) {
    int t = blockIdx.x * 256 + threadIdx.x;
    if (t >= 55296) return;
    int c, base, K;
    const float* src = nullptr;
    if (t < 13824)      { c = t;         base = 0;      K = 192; }
    else if (t < 18432) { c = t - 13824; base = 110592; K = 192; src = Wp; }
    else if (t < 36864) { c = t - 18432; base = 147456; K = 192; src = Wf1; }
    else                { c = t - 36864; base = 294912; K = 768; src = Wf2; }
    int lane = c & 63, fk = c >> 6, Kf = K >> 5;
    int kf = fk % Kf, nf = fk / Kf;
    int row = nf * 16 + (lane & 15), col = kf * 32 + (lane >> 4) * 8;
    ush8 o;
    if (t < 13824) {
        if (row < 192) {
            #pragma unroll
            for (int q = 0; q < 8; q++) o[q] = f2bf(Wq[row * 192 + col + q] * 0.17677669529663687f);
        } else {
            #pragma unroll
            for (int q = 0; q < 8; q++) o[q] = f2bf(Wkv[(row - 192) * 192 + col + q]);
        }
    } else {
        #pragma unroll
        for (int q = 0; q < 8; q++) o[q] = f2bf(src[(long)row * K + col + q]);
    }
    *(ush8*)&dst[base + c * 8] = o;
}

// ---------------- fused bias+mask table: [6 heads][8 variants][128 i][16 li][8 fn] f32 ----------------
__global__ __launch_bounds__(256) void k_bmt(const float* __restrict__ rpb, float* __restrict__ bmt) {
    int t = blockIdx.x * 256 + threadIdx.x;  // 6 * 131072
    int h = t >> 17;
    int r = t & 131071;
    int v = r >> 14;
    int ij = r & 16383;
    int i = ij >> 7, li = (ij >> 3) & 15, fn = ij & 7;
    int j = fn * 16 + li;
    int tdi = i >> 6, thi = (i >> 3) & 7, twi = i & 7;
    int tdj = j >> 6, thj = (j >> 3) & 7, twj = j & 7;
    int idx = ((tdi - tdj + 1) * 15 + (thi - thj + 7)) * 15 + (twi - twj + 7);
    float b = rpb[idx * 6 + h];
    int dwb = v & 1, hwb = (v >> 1) & 1, wwb = (v >> 2) & 1;
    int ri = (dwb ? 1 + tdi : 0) * 9 + (hwb ? (thi < 4 ? 1 : 2) : 0) * 3 + (wwb ? (twi < 4 ? 1 : 2) : 0);
    int rj = (dwb ? 1 + tdj : 0) * 9 + (hwb ? (thj < 4 ? 1 : 2) : 0) * 3 + (wwb ? (twj < 4 ? 1 : 2) : 0);
    if (ri != rj) b -= 100.f;
    bmt[(long)(h * 8 + v) * 16384 + i * 128 + li * 8 + fn] = b;
}

// ---------------- LayerNorm fused with roll+window gather ----------------
__global__ __launch_bounds__(256) void k_ln(const float* __restrict__ x, const float* __restrict__ g,
                                            const float* __restrict__ b, unsigned short* __restrict__ outp) {
    int wid = threadIdx.x >> 6, lane = threadIdx.x & 63;
    int t = blockIdx.x * 4 + wid;
    int w = t >> 7, tt = t & 127;
    int bb = w >> 8, rem = w & 255;
    int dw = rem >> 6, hw = (rem >> 3) & 7, ww = rem & 7;
    int td = tt >> 6, th = (tt >> 3) & 7, tw = tt & 7;
    int d = (dw * 2 + td + 1) & 7;
    int hh = (hw * 8 + th + 4) & 63;
    int wo = (ww * 8 + tw + 4) & 63;
    long src = (long)((bb * 8 + d) * 64 + hh) * 64 + wo;
    const float* xp = x + src * 192;
    float v0 = xp[lane], v1 = xp[lane + 64], v2 = xp[lane + 128];
    float s = v0 + v1 + v2, ss = v0 * v0 + v1 * v1 + v2 * v2;
    #pragma unroll
    for (int m = 32; m; m >>= 1) { s += __shfl_xor(s, m); ss += __shfl_xor(ss, m); }
    float mu = s * (1.f / 192.f);
    float var = ss * (1.f / 192.f) - mu * mu;
    float inv = rsqrtf(var + 1e-5f);
    unsigned short* op = outp + (long)t * 192;
    op[lane]       = f2bf((v0 - mu) * inv * g[lane]       + b[lane]);
    op[lane + 64]  = f2bf((v1 - mu) * inv * g[lane + 64]  + b[lane + 64]);
    op[lane + 128] = f2bf((v2 - mu) * inv * g[lane + 128] + b[lane + 128]);
}

// ---------------- bf16 MFMA GEMM: C[M,N] = A[M,K] @ B[N,K]^T, B in packed-frag form ----------------
// EPI: 1=proj + window-reverse + residual -> x1 bf16
template <int EPI>
__global__ __launch_bounds__(256, 4) void k_gemm(const unsigned short* __restrict__ A,
                                                 const unsigned short* __restrict__ Bpk, int K,
                                                 const float* __restrict__ bias,
                                                 const float* __restrict__ addsrc,
                                                 unsigned short* __restrict__ outU) {
    __shared__ __align__(16) unsigned short As[2][256 * 32];
    int tid = threadIdx.x;
    int wid = tid >> 6, lane = tid & 63;
    int g = lane >> 4, li = lane & 15;
    int m0 = blockIdx.y * 256, n0 = blockIdx.x * 64;
    int Kf = K >> 5;

    f32x4 acc[4][4];
    #pragma unroll
    for (int i = 0; i < 4; i++)
        #pragma unroll
        for (int j = 0; j < 4; j++) acc[i][j] = (f32x4){0.f, 0.f, 0.f, 0.f};

    int sg = ((tid & 3) ^ ((tid >> 3) & 3)) * 8;
    const unsigned short* pa = A + (long)(m0 + (tid >> 2)) * K + sg;
    const unsigned short* pbk = Bpk + ((long)(n0 >> 4) * Kf * 64 + lane) * 8;

#define STAGE(buf, kt) do { \
    _Pragma("unroll") \
    for (int c = 0; c < 4; c++) \
        gload16(pa + (long)(c * 64) * K + (kt), &As[buf][c * 2048 + tid * 8]); \
} while (0)

    STAGE(0, 0);
    __syncthreads();

    int cur = 0;
    int acol = (g ^ ((li >> 1) & 3)) * 8;
    for (int t = 0; t < Kf; t++) {
        bf16x8 bfr[4];
        #pragma unroll
        for (int j = 0; j < 4; j++)
            bfr[j] = *(const bf16x8*)(pbk + ((long)j * Kf + t) * 512);
        if (t + 1 < Kf) STAGE(cur ^ 1, (t + 1) << 5);
        const unsigned short* ab = &As[cur][(wid * 64 + li) * 32 + acol];
        bf16x8 af[4];
        #pragma unroll
        for (int i = 0; i < 4; i++) af[i] = *(const bf16x8*)(ab + i * 512);
        __builtin_amdgcn_s_setprio(1);
        #pragma unroll
        for (int i = 0; i < 4; i++)
            #pragma unroll
            for (int j = 0; j < 4; j++)
                acc[i][j] = __builtin_amdgcn_mfma_f32_16x16x32_bf16(af[i], bfr[j], acc[i][j], 0, 0, 0);
        __builtin_amdgcn_s_setprio(0);
        if (t + 1 < Kf) {
            __syncthreads();
            cur ^= 1;
        }
    }
#undef STAGE

    #pragma unroll
    for (int i = 0; i < 4; i++) {
        int rowb = m0 + wid * 64 + i * 16 + g * 4;
        #pragma unroll
        for (int j = 0; j < 4; j++) {
            int col = n0 + j * 16 + li;
            #pragma unroll
            for (int r = 0; r < 4; r++) {
                float v = acc[i][j][r];
                int rr = rowb + r;
                {
                    int w = rr >> 7, tt = rr & 127;
                    int bb2 = w >> 8, rem = w & 255;
                    int dw = rem >> 6, hw = (rem >> 3) & 7, ww = rem & 7;
                    int td = tt >> 6, th = (tt >> 3) & 7, tw = tt & 7;
                    int d = (dw * 2 + td + 1) & 7;
                    int hh = (hw * 8 + th + 4) & 63;
                    int wo = (ww * 8 + tw + 4) & 63;
                    long src = ((long)((bb2 * 8 + d) * 64 + hh) * 64 + wo) * 192 + col;
                    outU[src] = f2bf(addsrc[src] + v + bias[col]);   // x1 in bf16
                }
            }
        }
    }
}

// ---------------- fused LN2 + MLP1 + GELU + MLP2 + residual (x1 in bf16) ----------------
// One block = 64 token rows, 512 threads (8 waves). LDS in MFMA-FRAGMENT-PACKED layout
// (frag = 64 lanes x 16B contiguous -> conflict-free 1KB wave reads). 40KB LDS.
__global__ __launch_bounds__(512, 4) void k_mlp(const unsigned short* __restrict__ x1,
                                                const float* __restrict__ g2, const float* __restrict__ b2,
                                                const unsigned short* __restrict__ wf1pk,
                                                const unsigned short* __restrict__ wf2pk,
                                                const float* __restrict__ bf1v, const float* __restrict__ bf2v,
                                                float* __restrict__ out) {
    __shared__ __align__(16) unsigned short A_s[24 * 512];  // 24576 B
    __shared__ __align__(16) unsigned short H_s[16 * 512];  // 16384 B
    int tid = threadIdx.x;
    int wid = tid >> 6, lane = tid & 63;
    int g = lane >> 4, li = lane & 15;
    long r0 = (long)blockIdx.x * 64;

    // ---- LN2 stage: 8 threads per row, 24 bf16 each; write in packed-frag layout ----
    {
        int row = tid >> 3;
        int c0 = (tid & 7) * 24;
        const unsigned short* xp = x1 + (r0 + row) * 192 + c0;
        float v[24];
        #pragma unroll
        for (int q = 0; q < 3; q++) {
            ush8 f = *(const ush8*)(xp + q * 8);
            #pragma unroll
            for (int e = 0; e < 8; e++) v[q * 8 + e] = bf2f(f[e]);
        }
        float s = 0.f, ss = 0.f;
        #pragma unroll
        for (int q = 0; q < 24; q++) { s += v[q]; ss += v[q] * v[q]; }
        #pragma unroll
        for (int m = 1; m < 8; m <<= 1) { s += __shfl_xor(s, m); ss += __shfl_xor(ss, m); }
        float mu = s * (1.f / 192.f);
        float var = ss * (1.f / 192.f) - mu * mu;
        float inv = rsqrtf(var + 1e-5f);
        ush8 o[3];
        #pragma unroll
        for (int q = 0; q < 24; q++) {
            float gv = g2[c0 + q], bv = b2[c0 + q];
            o[q >> 3][q & 7] = f2bf((v[q] - mu) * inv * gv + bv);
        }
        #pragma unroll
        for (int q = 0; q < 3; q++) {
            int cb = c0 + q * 8;
            int fi = (row >> 4) * 6 + (cb >> 5);            // frag index (mf*6+kf)
            int l2 = (((cb >> 3) & 3) << 4) | (row & 15);   // dest lane in frag
            *(ush8*)&A_s[(fi * 64 + l2) * 8] = o[q];
        }
    }
    __syncthreads();

    int mw = wid >> 2, nw = wid & 3;            // GEMM2 roles: token half, out-col quarter
    int kf2 = wid >> 1;                          // this wave's hidden-frag in GEMM1 output
    int gpos = ((wid & 1) << 1) | (li >> 3);     // position-in-frag for H writes
    int e = li & 7;
    f32x4 acc2[2][3];
    #pragma unroll
    for (int i = 0; i < 2; i++)
        #pragma unroll
        for (int j = 0; j < 3; j++) acc2[i][j] = (f32x4){0.f, 0.f, 0.f, 0.f};

    for (int ch = 0; ch < 6; ch++) {
        // GEMM1: wave owns hidden frag nf = ch*8 + wid (16 cols), all 64 tokens
        f32x4 acc1[4];
        #pragma unroll
        for (int i = 0; i < 4; i++) acc1[i] = (f32x4){0.f, 0.f, 0.f, 0.f};
        int nf = ch * 8 + wid;
        float bv1 = bf1v[ch * 128 + wid * 16 + li];
        #pragma unroll
        for (int kf = 0; kf < 6; kf++) {
            bf16x8 b = *(const bf16x8*)&wf1pk[(((long)nf * 6 + kf) * 64 + lane) * 8];
            __builtin_amdgcn_s_setprio(1);
            #pragma unroll
            for (int mf = 0; mf < 4; mf++) {
                bf16x8 a = *(const bf16x8*)&A_s[(((mf * 6 + kf) * 64) + lane) * 8];
                acc1[mf] = __builtin_amdgcn_mfma_f32_16x16x32_bf16(a, b, acc1[mf], 0, 0, 0);
            }
            __builtin_amdgcn_s_setprio(0);
        }
        // hoist W2 loads for kf=0,1 across the barrier
        bf16x8 w2p[2][3];
        #pragma unroll
        for (int kf = 0; kf < 2; kf++)
            #pragma unroll
            for (int jf = 0; jf < 3; jf++)
                w2p[kf][jf] = *(const bf16x8*)&wf2pk[(((long)(nw * 3 + jf) * 24 + ch * 4 + kf) * 64 + lane) * 8];
        // bias + gelu + write H chunk in packed-frag layout
        #pragma unroll
        for (int mf = 0; mf < 4; mf++)
            #pragma unroll
            for (int r = 0; r < 4; r++) {
                int l2 = (gpos << 4) | (g * 4 + r);
                H_s[((mf * 4 + kf2) * 64 + l2) * 8 + e] = f2bf(fast_gelu(acc1[mf][r] + bv1));
            }
        __syncthreads();
        // GEMM2 partial: out[mw*32.., nw*48..] += H_chunk @ Wf2[:, ch-cols]^T
        #pragma unroll
        for (int kf = 0; kf < 4; kf++) {
            bf16x8 hf[2], bf[3];
            #pragma unroll
            for (int mf = 0; mf < 2; mf++)
                hf[mf] = *(const bf16x8*)&H_s[(((mw * 2 + mf) * 4 + kf) * 64 + lane) * 8];
            if (kf < 2) {
                #pragma unroll
                for (int jf = 0; jf < 3; jf++) bf[jf] = w2p[kf][jf];
            } else {
                #pragma unroll
                for (int jf = 0; jf < 3; jf++)
                    bf[jf] = *(const bf16x8*)&wf2pk[(((long)(nw * 3 + jf) * 24 + ch * 4 + kf) * 64 + lane) * 8];
            }
            __builtin_amdgcn_s_setprio(1);
            #pragma unroll
            for (int mf = 0; mf < 2; mf++)
                #pragma unroll
                for (int jf = 0; jf < 3; jf++)
                    acc2[mf][jf] = __builtin_amdgcn_mfma_f32_16x16x32_bf16(hf[mf], bf[jf], acc2[mf][jf], 0, 0, 0);
            __builtin_amdgcn_s_setprio(0);
        }
        __syncthreads();
    }

    // epilogue: out = x1 + acc2 + bf2
    #pragma unroll
    for (int mf = 0; mf < 2; mf++) {
        #pragma unroll
        for (int jf = 0; jf < 3; jf++) {
            int col = nw * 48 + jf * 16 + li;
            float bv = bf2v[col];
            #pragma unroll
            for (int r = 0; r < 4; r++) {
                int row = mw * 32 + mf * 16 + g * 4 + r;
                long idx = (r0 + row) * 192 + col;
                out[idx] = bf2f(x1[idx]) + acc2[mf][jf][r] + bv;
            }
        }
    }
}

// ---------------- attention with fused QKV: 3072 blocks, XCD-swizzled, 256 threads ----------------
// Block b -> xcd x=b%8, slot j=b/8 -> window w = x + 8*(j/6), head h = j%6 (same-XCD windows).
// QKV weight frags double-buffered in registers: kf+1's 6 loads issue under kf's 12 MFMAs.
// Post-QK^T barrier removed: p_s rows are wave-private (write+read by same wave), and the
// xw_s overlay is ordered by the scatter barrier.
__global__ __launch_bounds__(256, 2) void k_attn(const unsigned short* __restrict__ xw,
                                                 const unsigned short* __restrict__ qkvpk,
                                                 const float* __restrict__ bmt,
                                                 unsigned short* __restrict__ attnout) {
    __shared__ __align__(16) char smem[78336];
    unsigned short* xw_s = (unsigned short*)smem;            // [128][200] = 51200B, dead after QKV
    unsigned short* p_s  = (unsigned short*)smem;            // [128][132] = 33792B, overlays xw_s
    unsigned short* q_s  = (unsigned short*)(smem + 51200);  // [128][36]  = 9216B
    unsigned short* k_s  = (unsigned short*)(smem + 60416);  // [128][36]  = 9216B
    unsigned short* vt_s = (unsigned short*)(smem + 69632);  // [32][136]  = 8704B

    int b = blockIdx.x;
    int xcd = b & 7, j = b >> 3;
    int w = xcd + 8 * (j / 6), h = j % 6;
    int tid = threadIdx.x, wid = tid >> 6, lane = tid & 63, g = lane >> 4, li = lane & 15;
    int rem = w & 255;
    int dw = rem >> 6, hw = (rem >> 3) & 7, ww = rem & 7;
    int variant = (dw == 3 ? 1 : 0) | (hw == 7 ? 2 : 0) | (ww == 7 ? 4 : 0);
    const float* bm = bmt + (long)(h * 8 + variant) * 16384;

    // ---- stage xw tile [128][192] -> padded LDS [128][200] (2-way-free frag reads) ----
    {
        int r = tid >> 1, c0 = (tid & 1) * 96;
        const unsigned short* src = xw + ((long)w * 128 + r) * 192 + c0;
        #pragma unroll
        for (int jj = 0; jj < 12; jj++)
            *(uint4*)&xw_s[r * 200 + c0 + jj * 8] = *(const uint4*)(src + jj * 8);
    }
    __syncthreads();

    // ---- QKV: wave wid owns tokens wid*32..+31; frags jj: {q0,q1,k0,k1,v0,v1} ----
    f32x4 qk[2][6];
    #pragma unroll
    for (int i = 0; i < 2; i++)
        #pragma unroll
        for (int jj = 0; jj < 6; jj++) qk[i][jj] = (f32x4){0.f, 0.f, 0.f, 0.f};
    bf16x8 bwc[6];
    #pragma unroll
    for (int jj = 0; jj < 6; jj++) {
        int nf = (jj >> 1) * 12 + 2 * h + (jj & 1);
        bwc[jj] = *(const bf16x8*)&qkvpk[(((long)nf * 6 + 0) * 64 + lane) * 8];
    }
    #pragma unroll
    for (int kf = 0; kf < 6; kf++) {
        bf16x8 a0 = *(const bf16x8*)&xw_s[(wid * 32 + li) * 200 + kf * 32 + g * 8];
        bf16x8 a1 = *(const bf16x8*)&xw_s[(wid * 32 + 16 + li) * 200 + kf * 32 + g * 8];
        bf16x8 bwn[6];
        if (kf < 5) {
            #pragma unroll
            for (int jj = 0; jj < 6; jj++) {
                int nf = (jj >> 1) * 12 + 2 * h + (jj & 1);
                bwn[jj] = *(const bf16x8*)&qkvpk[(((long)nf * 6 + (kf + 1)) * 64 + lane) * 8];
            }
        }
        __builtin_amdgcn_s_setprio(1);
        #pragma unroll
        for (int jj = 0; jj < 6; jj++) {
            qk[0][jj] = __builtin_amdgcn_mfma_f32_16x16x32_bf16(a0, bwc[jj], qk[0][jj], 0, 0, 0);
            qk[1][jj] = __builtin_amdgcn_mfma_f32_16x16x32_bf16(a1, bwc[jj], qk[1][jj], 0, 0, 0);
        }
        __builtin_amdgcn_s_setprio(0);
        if (kf < 5) {
            #pragma unroll
            for (int jj = 0; jj < 6; jj++) bwc[jj] = bwn[jj];
        }
    }
    // scatter q/k/v into LDS (col=li, row=token g*4+r per C/D layout)
    #pragma unroll
    for (int mf = 0; mf < 2; mf++) {
        int tokb = wid * 32 + mf * 16 + g * 4;
        #pragma unroll
        for (int r = 0; r < 4; r++) {
            int tok = tokb + r;
            q_s[tok * 36 + li]          = f2bf(qk[mf][0][r]);
            q_s[tok * 36 + 16 + li]     = f2bf(qk[mf][1][r]);
            k_s[tok * 36 + li]          = f2bf(qk[mf][2][r]);
            k_s[tok * 36 + 16 + li]     = f2bf(qk[mf][3][r]);
            vt_s[li * 136 + tok]        = f2bf(qk[mf][4][r]);
            vt_s[(16 + li) * 136 + tok] = f2bf(qk[mf][5][r]);
        }
    }
    __syncthreads();   // all xw_s reads done; p_s may overlay from here on

    f32x4 s[2][8];
    #pragma unroll
    for (int i = 0; i < 2; i++)
        #pragma unroll
        for (int jj = 0; jj < 8; jj++) s[i][jj] = (f32x4){0.f, 0.f, 0.f, 0.f};
    bf16x8 qa[2];
    #pragma unroll
    for (int fm = 0; fm < 2; fm++)
        qa[fm] = *(const bf16x8*)&q_s[(wid * 32 + fm * 16 + li) * 36 + g * 8];
    __builtin_amdgcn_s_setprio(1);
    #pragma unroll
    for (int fn = 0; fn < 8; fn++) {
        bf16x8 kb = *(const bf16x8*)&k_s[(fn * 16 + li) * 36 + g * 8];
        s[0][fn] = __builtin_amdgcn_mfma_f32_16x16x32_bf16(qa[0], kb, s[0][fn], 0, 0, 0);
        s[1][fn] = __builtin_amdgcn_mfma_f32_16x16x32_bf16(qa[1], kb, s[1][fn], 0, 0, 0);
    }
    __builtin_amdgcn_s_setprio(0);
    // (no barrier: each wave writes/reads only its own p_s rows; overlay ordered by scatter barrier)

    #pragma unroll
    for (int fm = 0; fm < 2; fm++) {
        #pragma unroll
        for (int r = 0; r < 4; r++) {
            int i = wid * 32 + fm * 16 + g * 4 + r;
            const float4 b0 = *(const float4*)&bm[i * 128 + li * 8];
            const float4 b1 = *(const float4*)&bm[i * 128 + li * 8 + 4];
            float vals[8];
            vals[0] = s[fm][0][r] + b0.x; vals[1] = s[fm][1][r] + b0.y;
            vals[2] = s[fm][2][r] + b0.z; vals[3] = s[fm][3][r] + b0.w;
            vals[4] = s[fm][4][r] + b1.x; vals[5] = s[fm][5][r] + b1.y;
            vals[6] = s[fm][6][r] + b1.z; vals[7] = s[fm][7][r] + b1.w;
            float mx = fmaxf(fmaxf(fmaxf(vals[0], vals[1]), fmaxf(vals[2], vals[3])),
                             fmaxf(fmaxf(vals[4], vals[5]), fmaxf(vals[6], vals[7])));
            #pragma unroll
            for (int m = 1; m < 16; m <<= 1) mx = fmaxf(mx, __shfl_xor(mx, m, 16));
            float sum = 0.f;
            #pragma unroll
            for (int fn = 0; fn < 8; fn++) { vals[fn] = __expf(vals[fn] - mx); sum += vals[fn]; }
            #pragma unroll
            for (int m = 1; m < 16; m <<= 1) sum += __shfl_xor(sum, m, 16);
            float inv = __builtin_amdgcn_rcpf(sum);
            #pragma unroll
            for (int fn = 0; fn < 8; fn++)
                p_s[i * 132 + fn * 16 + li] = f2bf(vals[fn] * inv);
        }
    }

    f32x4 o[2][2];
    #pragma unroll
    for (int i = 0; i < 2; i++)
        #pragma unroll
        for (int jj = 0; jj < 2; jj++) o[i][jj] = (f32x4){0.f, 0.f, 0.f, 0.f};
    __builtin_amdgcn_s_setprio(1);
    #pragma unroll
    for (int ks = 0; ks < 4; ks++) {
        bf16x8 pa[2];
        #pragma unroll
        for (int fm = 0; fm < 2; fm++)
            pa[fm] = *(const bf16x8*)&p_s[(wid * 32 + fm * 16 + li) * 132 + ks * 32 + g * 8];
        #pragma unroll
        for (int fn = 0; fn < 2; fn++) {
            bf16x8 vb = *(const bf16x8*)&vt_s[(fn * 16 + li) * 136 + ks * 32 + g * 8];
            o[0][fn] = __builtin_amdgcn_mfma_f32_16x16x32_bf16(pa[0], vb, o[0][fn], 0, 0, 0);
            o[1][fn] = __builtin_amdgcn_mfma_f32_16x16x32_bf16(pa[1], vb, o[1][fn], 0, 0, 0);
        }
    }
    __builtin_amdgcn_s_setprio(0);

    unsigned short* op = attnout + (long)w * 128 * 192 + h * 32;
    #pragma unroll
    for (int fm = 0; fm < 2; fm++) {
        #pragma unroll
        for (int fn = 0; fn < 2; fn++) {
            #pragma unroll
            for (int r = 0; r < 4; r++) {
                int n = wid * 32 + fm * 16 + g * 4 + r;
                op[(long)n * 192 + fn * 16 + li] = f2bf(o[fm][fn][r]);
            }
        }
    }
}

// ---------------- host ----------------
extern "C" void kernel_launch(void* const* d_in, const int* in_sizes, int n_in,
                              void* d_out, int out_size, void* d_ws, size_t ws_size,
                              hipStream_t stream) {
    const float* x   = (const float*)d_in[0];
    const float* g1  = (const float*)d_in[1];
    const float* b1  = (const float*)d_in[2];
    const float* Wq  = (const float*)d_in[3];
    const float* Wkv = (const float*)d_in[4];
    const float* rpb = (const float*)d_in[5];
    const float* Wp  = (const float*)d_in[6];
    const float* bp  = (const float*)d_in[7];
    const float* g2  = (const float*)d_in[8];
    const float* b2  = (const float*)d_in[9];
    const float* Wf1 = (const float*)d_in[10];
    const float* bf1 = (const float*)d_in[11];
    const float* Wf2 = (const float*)d_in[12];
    const float* bf2 = (const float*)d_in[13];
    float* out = (float*)d_out;
    char* ws = (char*)d_ws;

    unsigned short* wpk  = (unsigned short*)ws;               // 884736 B
    float* bmt           = (float*)(ws + 917504);             // 3145728 B -> ends 4063232
    unsigned short* xw   = (unsigned short*)(ws + 4194304);   // 25165824 B -> ends 29360128
    unsigned short* attb = (unsigned short*)(ws + 29360128);  // 25165824 B -> ends 54525952
    unsigned short* x1b  = (unsigned short*)(ws + 54525952);  // 25165824 B bf16 -> ends 79691776

    const unsigned short* qkvpk = wpk;
    const unsigned short* wppk  = wpk + 110592;
    const unsigned short* wf1pk = wpk + 147456;
    const unsigned short* wf2pk = wpk + 294912;

    k_pack<<<216, 256, 0, stream>>>(Wq, Wkv, Wp, Wf1, Wf2, wpk);
    k_bmt<<<3072, 256, 0, stream>>>(rpb, bmt);
    k_ln<<<16384, 256, 0, stream>>>(x, g1, b1, xw);
    k_attn<<<3072, 256, 0, stream>>>(xw, qkvpk, bmt, attb);
    k_gemm<1><<<dim3(3, 256), 256, 0, stream>>>(attb, wppk, 192, bp, x, x1b);
    k_mlp<<<1024, 512, 0, stream>>>(x1b, g2, b2, wf1pk, wf2pk, bf1, bf2, out);
}

// Round 22
// 156.637 us; speedup vs baseline: 1.2424x; 1.1664x over previous
//
#include <hip/hip_runtime.h>
#include <cstdint>

#define DEVI static __device__ __forceinline__

typedef __attribute__((ext_vector_type(8))) short bf16x8;
typedef __attribute__((ext_vector_type(4))) float f32x4;
typedef __attribute__((ext_vector_type(8))) unsigned short ush8;

DEVI unsigned short f2bf(float f) {
    unsigned u = __float_as_uint(f);
    u += 0x7fff + ((u >> 16) & 1);
    return (unsigned short)(u >> 16);
}
DEVI float bf2f(unsigned short h) { return __uint_as_float(((unsigned)h) << 16); }

DEVI void gload16(const void* g, void* l) {
    __builtin_amdgcn_global_load_lds((const __attribute__((address_space(1))) void*)g,
                                     (__attribute__((address_space(3))) void*)l, 16, 0, 0);
}

DEVI float fast_gelu(float x) {
    // tanh-approx GELU via raw v_rcp_f32 (no -ffast-math; '/' would expand to ~12-op exact div)
    float z = 1.5957691216057308f * (x + 0.044715f * x * x * x);
    return x - x * __builtin_amdgcn_rcpf(__expf(z) + 1.f);
}

// ---------------- weight pack: fp32 -> bf16 in MFMA-fragment order ----------------
__global__ __launch_bounds__(256) void k_pack(const float* __restrict__ Wq, const float* __restrict__ Wkv,
                                              const float* __restrict__ Wp, const float* __restrict__ Wf1,
                                              const float* __restrict__ Wf2, unsigned short* __restrict__ dst) {
    int t = blockIdx.x * 256 + threadIdx.x;
    if (t >= 55296) return;
    int c, base, K;
    const float* src = nullptr;
    if (t < 13824)      { c = t;         base = 0;      K = 192; }
    else if (t < 18432) { c = t - 13824; base = 110592; K = 192; src = Wp; }
    else if (t < 36864) { c = t - 18432; base = 147456; K = 192; src = Wf1; }
    else                { c = t - 36864; base = 294912; K = 768; src = Wf2; }
    int lane = c & 63, fk = c >> 6, Kf = K >> 5;
    int kf = fk % Kf, nf = fk / Kf;
    int row = nf * 16 + (lane & 15), col = kf * 32 + (lane >> 4) * 8;
    ush8 o;
    if (t < 13824) {
        if (row < 192) {
            #pragma unroll
            for (int q = 0; q < 8; q++) o[q] = f2bf(Wq[row * 192 + col + q] * 0.17677669529663687f);
        } else {
            #pragma unroll
            for (int q = 0; q < 8; q++) o[q] = f2bf(Wkv[(row - 192) * 192 + col + q]);
        }
    } else {
        #pragma unroll
        for (int q = 0; q < 8; q++) o[q] = f2bf(src[(long)row * K + col + q]);
    }
    *(ush8*)&dst[base + c * 8] = o;
}

// ---------------- fused bias+mask table: [6 heads][8 variants][128 i][16 li][8 fn] f32 ----------------
__global__ __launch_bounds__(256) void k_bmt(const float* __restrict__ rpb, float* __restrict__ bmt) {
    int t = blockIdx.x * 256 + threadIdx.x;  // 6 * 131072
    int h = t >> 17;
    int r = t & 131071;
    int v = r >> 14;
    int ij = r & 16383;
    int i = ij >> 7, li = (ij >> 3) & 15, fn = ij & 7;
    int j = fn * 16 + li;
    int tdi = i >> 6, thi = (i >> 3) & 7, twi = i & 7;
    int tdj = j >> 6, thj = (j >> 3) & 7, twj = j & 7;
    int idx = ((tdi - tdj + 1) * 15 + (thi - thj + 7)) * 15 + (twi - twj + 7);
    float b = rpb[idx * 6 + h];
    int dwb = v & 1, hwb = (v >> 1) & 1, wwb = (v >> 2) & 1;
    int ri = (dwb ? 1 + tdi : 0) * 9 + (hwb ? (thi < 4 ? 1 : 2) : 0) * 3 + (wwb ? (twi < 4 ? 1 : 2) : 0);
    int rj = (dwb ? 1 + tdj : 0) * 9 + (hwb ? (thj < 4 ? 1 : 2) : 0) * 3 + (wwb ? (twj < 4 ? 1 : 2) : 0);
    if (ri != rj) b -= 100.f;
    bmt[(long)(h * 8 + v) * 16384 + i * 128 + li * 8 + fn] = b;
}

// ---------------- LayerNorm fused with roll+window gather; OUTPUT IN PACKED-FRAG FORM ----------------
// xwpk layout: window w, frag (mf 0..7, kf 0..5) = 64 lanes x 8 shorts; lane gg*16+ll holds
// xw[token w*128+mf*16+ll][chan kf*32+gg*8 .. +8].
__global__ __launch_bounds__(256) void k_ln(const float* __restrict__ x, const float* __restrict__ g,
                                            const float* __restrict__ b, unsigned short* __restrict__ xwpk) {
    int wid = threadIdx.x >> 6, lane = threadIdx.x & 63;
    int t = blockIdx.x * 4 + wid;
    int w = t >> 7, tt = t & 127;
    int bb = w >> 8, rem = w & 255;
    int dw = rem >> 6, hw = (rem >> 3) & 7, ww = rem & 7;
    int td = tt >> 6, th = (tt >> 3) & 7, tw = tt & 7;
    int d = (dw * 2 + td + 1) & 7;
    int hh = (hw * 8 + th + 4) & 63;
    int wo = (ww * 8 + tw + 4) & 63;
    long src = (long)((bb * 8 + d) * 64 + hh) * 64 + wo;
    const float* xp = x + src * 192;
    float v0 = xp[lane], v1 = xp[lane + 64], v2 = xp[lane + 128];
    float s = v0 + v1 + v2, ss = v0 * v0 + v1 * v1 + v2 * v2;
    #pragma unroll
    for (int m = 32; m; m >>= 1) { s += __shfl_xor(s, m); ss += __shfl_xor(ss, m); }
    float mu = s * (1.f / 192.f);
    float var = ss * (1.f / 192.f) - mu * mu;
    float inv = rsqrtf(var + 1e-5f);
    int mfq = tt >> 4, rowf = tt & 15;
    long base = ((long)w * 48 + mfq * 6) * 512;
    #pragma unroll
    for (int q = 0; q < 3; q++) {
        int c = lane + q * 64;
        float vv = (q == 0 ? v0 : (q == 1 ? v1 : v2));
        float y = (vv - mu) * inv * g[c] + b[c];
        xwpk[base + (c >> 5) * 512 + ((((c >> 3) & 3) << 4) + rowf) * 8 + (c & 7)] = f2bf(y);
    }
}

// ---------------- bf16 MFMA GEMM: C[M,N] = A[M,K] @ B[N,K]^T, B in packed-frag form ----------------
// EPI: 1=proj + window-reverse + residual -> x1 bf16
template <int EPI>
__global__ __launch_bounds__(256, 4) void k_gemm(const unsigned short* __restrict__ A,
                                                 const unsigned short* __restrict__ Bpk, int K,
                                                 const float* __restrict__ bias,
                                                 const float* __restrict__ addsrc,
                                                 unsigned short* __restrict__ outU) {
    __shared__ __align__(16) unsigned short As[2][256 * 32];
    int tid = threadIdx.x;
    int wid = tid >> 6, lane = tid & 63;
    int g = lane >> 4, li = lane & 15;
    int m0 = blockIdx.y * 256, n0 = blockIdx.x * 64;
    int Kf = K >> 5;

    f32x4 acc[4][4];
    #pragma unroll
    for (int i = 0; i < 4; i++)
        #pragma unroll
        for (int j = 0; j < 4; j++) acc[i][j] = (f32x4){0.f, 0.f, 0.f, 0.f};

    int sg = ((tid & 3) ^ ((tid >> 3) & 3)) * 8;
    const unsigned short* pa = A + (long)(m0 + (tid >> 2)) * K + sg;
    const unsigned short* pbk = Bpk + ((long)(n0 >> 4) * Kf * 64 + lane) * 8;

#define STAGE(buf, kt) do { \
    _Pragma("unroll") \
    for (int c = 0; c < 4; c++) \
        gload16(pa + (long)(c * 64) * K + (kt), &As[buf][c * 2048 + tid * 8]); \
} while (0)

    STAGE(0, 0);
    __syncthreads();

    int cur = 0;
    int acol = (g ^ ((li >> 1) & 3)) * 8;
    for (int t = 0; t < Kf; t++) {
        bf16x8 bfr[4];
        #pragma unroll
        for (int j = 0; j < 4; j++)
            bfr[j] = *(const bf16x8*)(pbk + ((long)j * Kf + t) * 512);
        if (t + 1 < Kf) STAGE(cur ^ 1, (t + 1) << 5);
        const unsigned short* ab = &As[cur][(wid * 64 + li) * 32 + acol];
        bf16x8 af[4];
        #pragma unroll
        for (int i = 0; i < 4; i++) af[i] = *(const bf16x8*)(ab + i * 512);
        __builtin_amdgcn_s_setprio(1);
        #pragma unroll
        for (int i = 0; i < 4; i++)
            #pragma unroll
            for (int j = 0; j < 4; j++)
                acc[i][j] = __builtin_amdgcn_mfma_f32_16x16x32_bf16(af[i], bfr[j], acc[i][j], 0, 0, 0);
        __builtin_amdgcn_s_setprio(0);
        if (t + 1 < Kf) {
            __syncthreads();
            cur ^= 1;
        }
    }
#undef STAGE

    #pragma unroll
    for (int i = 0; i < 4; i++) {
        int rowb = m0 + wid * 64 + i * 16 + g * 4;
        #pragma unroll
        for (int j = 0; j < 4; j++) {
            int col = n0 + j * 16 + li;
            #pragma unroll
            for (int r = 0; r < 4; r++) {
                float v = acc[i][j][r];
                int rr = rowb + r;
                {
                    int w = rr >> 7, tt = rr & 127;
                    int bb2 = w >> 8, rem = w & 255;
                    int dw = rem >> 6, hw = (rem >> 3) & 7, ww = rem & 7;
                    int td = tt >> 6, th = (tt >> 3) & 7, tw = tt & 7;
                    int d = (dw * 2 + td + 1) & 7;
                    int hh = (hw * 8 + th + 4) & 63;
                    int wo = (ww * 8 + tw + 4) & 63;
                    long src = ((long)((bb2 * 8 + d) * 64 + hh) * 64 + wo) * 192 + col;
                    outU[src] = f2bf(addsrc[src] + v + bias[col]);   // x1 in bf16
                }
            }
        }
    }
}

// ---------------- fused LN2 + MLP1 + GELU + MLP2 + residual (x1 in bf16) ----------------
__global__ __launch_bounds__(512, 4) void k_mlp(const unsigned short* __restrict__ x1,
                                                const float* __restrict__ g2, const float* __restrict__ b2,
                                                const unsigned short* __restrict__ wf1pk,
                                                const unsigned short* __restrict__ wf2pk,
                                                const float* __restrict__ bf1v, const float* __restrict__ bf2v,
                                                float* __restrict__ out) {
    __shared__ __align__(16) unsigned short A_s[24 * 512];  // 24576 B
    __shared__ __align__(16) unsigned short H_s[16 * 512];  // 16384 B
    int tid = threadIdx.x;
    int wid = tid >> 6, lane = tid & 63;
    int g = lane >> 4, li = lane & 15;
    long r0 = (long)blockIdx.x * 64;

    {
        int row = tid >> 3;
        int c0 = (tid & 7) * 24;
        const unsigned short* xp = x1 + (r0 + row) * 192 + c0;
        float v[24];
        #pragma unroll
        for (int q = 0; q < 3; q++) {
            ush8 f = *(const ush8*)(xp + q * 8);
            #pragma unroll
            for (int e = 0; e < 8; e++) v[q * 8 + e] = bf2f(f[e]);
        }
        float s = 0.f, ss = 0.f;
        #pragma unroll
        for (int q = 0; q < 24; q++) { s += v[q]; ss += v[q] * v[q]; }
        #pragma unroll
        for (int m = 1; m < 8; m <<= 1) { s += __shfl_xor(s, m); ss += __shfl_xor(ss, m); }
        float mu = s * (1.f / 192.f);
        float var = ss * (1.f / 192.f) - mu * mu;
        float inv = rsqrtf(var + 1e-5f);
        ush8 o[3];
        #pragma unroll
        for (int q = 0; q < 24; q++) {
            float gv = g2[c0 + q], bv = b2[c0 + q];
            o[q >> 3][q & 7] = f2bf((v[q] - mu) * inv * gv + bv);
        }
        #pragma unroll
        for (int q = 0; q < 3; q++) {
            int cb = c0 + q * 8;
            int fi = (row >> 4) * 6 + (cb >> 5);
            int l2 = (((cb >> 3) & 3) << 4) | (row & 15);
            *(ush8*)&A_s[(fi * 64 + l2) * 8] = o[q];
        }
    }
    __syncthreads();

    int mw = wid >> 2, nw = wid & 3;
    int kf2 = wid >> 1;
    int gpos = ((wid & 1) << 1) | (li >> 3);
    int e = li & 7;
    f32x4 acc2[2][3];
    #pragma unroll
    for (int i = 0; i < 2; i++)
        #pragma unroll
        for (int j = 0; j < 3; j++) acc2[i][j] = (f32x4){0.f, 0.f, 0.f, 0.f};

    for (int ch = 0; ch < 6; ch++) {
        f32x4 acc1[4];
        #pragma unroll
        for (int i = 0; i < 4; i++) acc1[i] = (f32x4){0.f, 0.f, 0.f, 0.f};
        int nf = ch * 8 + wid;
        float bv1 = bf1v[ch * 128 + wid * 16 + li];
        #pragma unroll
        for (int kf = 0; kf < 6; kf++) {
            bf16x8 b = *(const bf16x8*)&wf1pk[(((long)nf * 6 + kf) * 64 + lane) * 8];
            __builtin_amdgcn_s_setprio(1);
            #pragma unroll
            for (int mf = 0; mf < 4; mf++) {
                bf16x8 a = *(const bf16x8*)&A_s[(((mf * 6 + kf) * 64) + lane) * 8];
                acc1[mf] = __builtin_amdgcn_mfma_f32_16x16x32_bf16(a, b, acc1[mf], 0, 0, 0);
            }
            __builtin_amdgcn_s_setprio(0);
        }
        bf16x8 w2p[2][3];
        #pragma unroll
        for (int kf = 0; kf < 2; kf++)
            #pragma unroll
            for (int jf = 0; jf < 3; jf++)
                w2p[kf][jf] = *(const bf16x8*)&wf2pk[(((long)(nw * 3 + jf) * 24 + ch * 4 + kf) * 64 + lane) * 8];
        #pragma unroll
        for (int mf = 0; mf < 4; mf++)
            #pragma unroll
            for (int r = 0; r < 4; r++) {
                int l2 = (gpos << 4) | (g * 4 + r);
                H_s[((mf * 4 + kf2) * 64 + l2) * 8 + e] = f2bf(fast_gelu(acc1[mf][r] + bv1));
            }
        __syncthreads();
        #pragma unroll
        for (int kf = 0; kf < 4; kf++) {
            bf16x8 hf[2], bf[3];
            #pragma unroll
            for (int mf = 0; mf < 2; mf++)
                hf[mf] = *(const bf16x8*)&H_s[(((mw * 2 + mf) * 4 + kf) * 64 + lane) * 8];
            if (kf < 2) {
                #pragma unroll
                for (int jf = 0; jf < 3; jf++) bf[jf] = w2p[kf][jf];
            } else {
                #pragma unroll
                for (int jf = 0; jf < 3; jf++)
                    bf[jf] = *(const bf16x8*)&wf2pk[(((long)(nw * 3 + jf) * 24 + ch * 4 + kf) * 64 + lane) * 8];
            }
            __builtin_amdgcn_s_setprio(1);
            #pragma unroll
            for (int mf = 0; mf < 2; mf++)
                #pragma unroll
                for (int jf = 0; jf < 3; jf++)
                    acc2[mf][jf] = __builtin_amdgcn_mfma_f32_16x16x32_bf16(hf[mf], bf[jf], acc2[mf][jf], 0, 0, 0);
            __builtin_amdgcn_s_setprio(0);
        }
        __syncthreads();
    }

    #pragma unroll
    for (int mf = 0; mf < 2; mf++) {
        #pragma unroll
        for (int jf = 0; jf < 3; jf++) {
            int col = nw * 48 + jf * 16 + li;
            float bv = bf2v[col];
            #pragma unroll
            for (int r = 0; r < 4; r++) {
                int row = mw * 32 + mf * 16 + g * 4 + r;
                long idx = (r0 + row) * 192 + col;
                out[idx] = bf2f(x1[idx]) + acc2[mf][jf][r] + bv;
            }
        }
    }
}

// ---------------- attention, fully fragment-packed: 3072 blocks XCD-swizzled, 3 blocks/CU ----------------
// xw read straight from global packed frags (coalesced, L2-hot). LDS: p_pk 32KB (q temp lives
// in each wave's own p slots) + k_pk 8KB + vt_pk 8KB = 48KB -> 3 blocks/CU (12 waves).
// One barrier total (after k/v/q scatter); everything else ordered by wave-local dataflow.
__global__ __launch_bounds__(256, 3) void k_attn(const unsigned short* __restrict__ xwpk,
                                                 const unsigned short* __restrict__ qkvpk,
                                                 const float* __restrict__ bmt,
                                                 unsigned short* __restrict__ attnout) {
    __shared__ __align__(16) unsigned short p_pk[32 * 512];   // 32768B; wave wid owns frags [wid*8, wid*8+8)
    __shared__ __align__(16) unsigned short k_pk[8 * 512];    // 8192B
    __shared__ __align__(16) unsigned short vt_pk[8 * 512];   // 8192B

    int b = blockIdx.x;
    int xcd = b & 7, jd = b >> 3;
    int w = xcd + 8 * (jd / 6), h = jd % 6;
    int tid = threadIdx.x, wid = tid >> 6, lane = tid & 63, g = lane >> 4, li = lane & 15;
    int rem = w & 255;
    int dw = rem >> 6, hw = (rem >> 3) & 7, ww = rem & 7;
    int variant = (dw == 3 ? 1 : 0) | (hw == 7 ? 2 : 0) | (ww == 7 ? 4 : 0);
    const float* bm = bmt + (long)(h * 8 + variant) * 16384;
    const unsigned short* xwb = xwpk + (long)w * 48 * 512;

    // ---- QKV: A-frags from global packed xw; weight frags double-buffered in regs ----
    f32x4 qk[2][6];
    #pragma unroll
    for (int i = 0; i < 2; i++)
        #pragma unroll
        for (int jj = 0; jj < 6; jj++) qk[i][jj] = (f32x4){0.f, 0.f, 0.f, 0.f};
    bf16x8 a0c = *(const bf16x8*)&xwb[(((wid * 2 + 0) * 6 + 0) * 64 + lane) * 8];
    bf16x8 a1c = *(const bf16x8*)&xwb[(((wid * 2 + 1) * 6 + 0) * 64 + lane) * 8];
    bf16x8 bwc[6];
    #pragma unroll
    for (int jj = 0; jj < 6; jj++) {
        int nf = (jj >> 1) * 12 + 2 * h + (jj & 1);
        bwc[jj] = *(const bf16x8*)&qkvpk[(((long)nf * 6 + 0) * 64 + lane) * 8];
    }
    #pragma unroll
    for (int kf = 0; kf < 6; kf++) {
        bf16x8 a0n, a1n, bwn[6];
        if (kf < 5) {
            a0n = *(const bf16x8*)&xwb[(((wid * 2 + 0) * 6 + kf + 1) * 64 + lane) * 8];
            a1n = *(const bf16x8*)&xwb[(((wid * 2 + 1) * 6 + kf + 1) * 64 + lane) * 8];
            #pragma unroll
            for (int jj = 0; jj < 6; jj++) {
                int nf = (jj >> 1) * 12 + 2 * h + (jj & 1);
                bwn[jj] = *(const bf16x8*)&qkvpk[(((long)nf * 6 + (kf + 1)) * 64 + lane) * 8];
            }
        }
        __builtin_amdgcn_s_setprio(1);
        #pragma unroll
        for (int jj = 0; jj < 6; jj++) {
            qk[0][jj] = __builtin_amdgcn_mfma_f32_16x16x32_bf16(a0c, bwc[jj], qk[0][jj], 0, 0, 0);
            qk[1][jj] = __builtin_amdgcn_mfma_f32_16x16x32_bf16(a1c, bwc[jj], qk[1][jj], 0, 0, 0);
        }
        __builtin_amdgcn_s_setprio(0);
        if (kf < 5) {
            a0c = a0n; a1c = a1n;
            #pragma unroll
            for (int jj = 0; jj < 6; jj++) bwc[jj] = bwn[jj];
        }
    }

    // ---- scatter q (into own p slots), k, v into packed-frag LDS ----
    #pragma unroll
    for (int fm = 0; fm < 2; fm++) {
        #pragma unroll
        for (int r = 0; r < 4; r++) {
            int ll = g * 4 + r;
            // q (j=0,1): frag id wid*8+fm (wave-private temp inside p_pk)
            p_pk[((wid * 8 + fm) * 64 + ((0 + (li >> 3)) << 4) + ll) * 8 + (li & 7)] = f2bf(qk[fm][0][r]);
            p_pk[((wid * 8 + fm) * 64 + ((2 + (li >> 3)) << 4) + ll) * 8 + (li & 7)] = f2bf(qk[fm][1][r]);
            // k (j=2,3): frag id wid*2+fm
            k_pk[((wid * 2 + fm) * 64 + ((0 + (li >> 3)) << 4) + ll) * 8 + (li & 7)] = f2bf(qk[fm][2][r]);
            k_pk[((wid * 2 + fm) * 64 + ((2 + (li >> 3)) << 4) + ll) * 8 + (li & 7)] = f2bf(qk[fm][3][r]);
            // v (j=4,5): vt frag (fn=j&1, ks=wid)
            vt_pk[((0 * 4 + wid) * 64 + ((fm * 2 + (g >> 1)) << 4) + li) * 8 + ((g & 1) * 4 + r)] = f2bf(qk[fm][4][r]);
            vt_pk[((1 * 4 + wid) * 64 + ((fm * 2 + (g >> 1)) << 4) + li) * 8 + ((g & 1) * 4 + r)] = f2bf(qk[fm][5][r]);
        }
    }
    __syncthreads();

    // ---- QK^T ----
    bf16x8 qa[2];
    qa[0] = *(const bf16x8*)&p_pk[((wid * 8 + 0) * 64 + lane) * 8];
    qa[1] = *(const bf16x8*)&p_pk[((wid * 8 + 1) * 64 + lane) * 8];
    f32x4 s[2][8];
    #pragma unroll
    for (int i = 0; i < 2; i++)
        #pragma unroll
        for (int jj = 0; jj < 8; jj++) s[i][jj] = (f32x4){0.f, 0.f, 0.f, 0.f};
    __builtin_amdgcn_s_setprio(1);
    #pragma unroll
    for (int fn = 0; fn < 8; fn++) {
        bf16x8 kb = *(const bf16x8*)&k_pk[(fn * 64 + lane) * 8];
        s[0][fn] = __builtin_amdgcn_mfma_f32_16x16x32_bf16(qa[0], kb, s[0][fn], 0, 0, 0);
        s[1][fn] = __builtin_amdgcn_mfma_f32_16x16x32_bf16(qa[1], kb, s[1][fn], 0, 0, 0);
    }
    __builtin_amdgcn_s_setprio(0);

    // ---- bias + mask + softmax; P stored in own packed frags (overwrites q temp; ordered by dataflow) ----
    #pragma unroll
    for (int fm = 0; fm < 2; fm++) {
        #pragma unroll
        for (int r = 0; r < 4; r++) {
            int i = wid * 32 + fm * 16 + g * 4 + r;
            const float4 b0 = *(const float4*)&bm[i * 128 + li * 8];
            const float4 b1 = *(const float4*)&bm[i * 128 + li * 8 + 4];
            float vals[8];
            vals[0] = s[fm][0][r] + b0.x; vals[1] = s[fm][1][r] + b0.y;
            vals[2] = s[fm][2][r] + b0.z; vals[3] = s[fm][3][r] + b0.w;
            vals[4] = s[fm][4][r] + b1.x; vals[5] = s[fm][5][r] + b1.y;
            vals[6] = s[fm][6][r] + b1.z; vals[7] = s[fm][7][r] + b1.w;
            float mx = fmaxf(fmaxf(fmaxf(vals[0], vals[1]), fmaxf(vals[2], vals[3])),
                             fmaxf(fmaxf(vals[4], vals[5]), fmaxf(vals[6], vals[7])));
            #pragma unroll
            for (int m = 1; m < 16; m <<= 1) mx = fmaxf(mx, __shfl_xor(mx, m, 16));
            float sum = 0.f;
            #pragma unroll
            for (int fn = 0; fn < 8; fn++) { vals[fn] = __expf(vals[fn] - mx); sum += vals[fn]; }
            #pragma unroll
            for (int m = 1; m < 16; m <<= 1) sum += __shfl_xor(sum, m, 16);
            float inv = __builtin_amdgcn_rcpf(sum);
            int ll = g * 4 + r;
            #pragma unroll
            for (int fn = 0; fn < 8; fn++)
                p_pk[((wid * 8 + fm * 4 + (fn >> 1)) * 64 + ((((fn & 1) << 1) + (li >> 3)) << 4) + ll) * 8 + (li & 7)]
                    = f2bf(vals[fn] * inv);
        }
    }

    // ---- PV: own p frags (wave-local, dataflow-ordered) x vt frags ----
    f32x4 o[2][2];
    #pragma unroll
    for (int i = 0; i < 2; i++)
        #pragma unroll
        for (int jj = 0; jj < 2; jj++) o[i][jj] = (f32x4){0.f, 0.f, 0.f, 0.f};
    __builtin_amdgcn_s_setprio(1);
    #pragma unroll
    for (int ks = 0; ks < 4; ks++) {
        bf16x8 pa[2];
        #pragma unroll
        for (int fm = 0; fm < 2; fm++)
            pa[fm] = *(const bf16x8*)&p_pk[((wid * 8 + fm * 4 + ks) * 64 + lane) * 8];
        #pragma unroll
        for (int fn = 0; fn < 2; fn++) {
            bf16x8 vb = *(const bf16x8*)&vt_pk[((fn * 4 + ks) * 64 + lane) * 8];
            o[0][fn] = __builtin_amdgcn_mfma_f32_16x16x32_bf16(pa[0], vb, o[0][fn], 0, 0, 0);
            o[1][fn] = __builtin_amdgcn_mfma_f32_16x16x32_bf16(pa[1], vb, o[1][fn], 0, 0, 0);
        }
    }
    __builtin_amdgcn_s_setprio(0);

    unsigned short* op = attnout + (long)w * 128 * 192 + h * 32;
    #pragma unroll
    for (int fm = 0; fm < 2; fm++) {
        #pragma unroll
        for (int fn = 0; fn < 2; fn++) {
            #pragma unroll
            for (int r = 0; r < 4; r++) {
                int n = wid * 32 + fm * 16 + g * 4 + r;
                op[(long)n * 192 + fn * 16 + li] = f2bf(o[fm][fn][r]);
            }
        }
    }
}

// ---------------- host ----------------
extern "C" void kernel_launch(void* const* d_in, const int* in_sizes, int n_in,
                              void* d_out, int out_size, void* d_ws, size_t ws_size,
                              hipStream_t stream) {
    const float* x   = (const float*)d_in[0];
    const float* g1  = (const float*)d_in[1];
    const float* b1  = (const float*)d_in[2];
    const float* Wq  = (const float*)d_in[3];
    const float* Wkv = (const float*)d_in[4];
    const float* rpb = (const float*)d_in[5];
    const float* Wp  = (const float*)d_in[6];
    const float* bp  = (const float*)d_in[7];
    const float* g2  = (const float*)d_in[8];
    const float* b2  = (const float*)d_in[9];
    const float* Wf1 = (const float*)d_in[10];
    const float* bf1 = (const float*)d_in[11];
    const float* Wf2 = (const float*)d_in[12];
    const float* bf2 = (const float*)d_in[13];
    float* out = (float*)d_out;
    char* ws = (char*)d_ws;

    unsigned short* wpk  = (unsigned short*)ws;               // 884736 B
    float* bmt           = (float*)(ws + 917504);             // 3145728 B -> ends 4063232
    unsigned short* xwp  = (unsigned short*)(ws + 4194304);   // 25165824 B (packed frags) -> ends 29360128
    unsigned short* attb = (unsigned short*)(ws + 29360128);  // 25165824 B -> ends 54525952
    unsigned short* x1b  = (unsigned short*)(ws + 54525952);  // 25165824 B bf16 -> ends 79691776

    const unsigned short* qkvpk = wpk;
    const unsigned short* wppk  = wpk + 110592;
    const unsigned short* wf1pk = wpk + 147456;
    const unsigned short* wf2pk = wpk + 294912;

    k_pack<<<216, 256, 0, stream>>>(Wq, Wkv, Wp, Wf1, Wf2, wpk);
    k_bmt<<<3072, 256, 0, stream>>>(rpb, bmt);
    k_ln<<<16384, 256, 0, stream>>>(x, g1, b1, xwp);
    k_attn<<<3072, 256, 0, stream>>>(xwp, qkvpk, bmt, attb);
    k_gemm<1><<<dim3(3, 256), 256, 0, stream>>>(attb, wppk, 192, bp, x, x1b);
    k_mlp<<<1024, 512, 0, stream>>>(x1b, g2, b2, wf1pk, wf2pk, bf1, bf2, out);
}